// Round 12
// baseline (304.380 us; speedup 1.0000x reference)
//
#include <hip/hip_runtime.h>

#define D 128
#define PAD 40
#define NBT 256      // max buckets per node type
#define DNMAX 512    // max dsts per bucket
#define GT 32        // dst rows per gather tile
#define GCAP 1536    // staged col window cap (ints)

typedef __attribute__((ext_vector_type(8))) short short8;
typedef __attribute__((ext_vector_type(4))) float f32x4;

__device__ __forceinline__ unsigned short f2bf(float x) {
    union { float f; unsigned u; } v; v.f = x;
    unsigned r = v.u + 0x7fff + ((v.u >> 16) & 1);   // RNE
    return (unsigned short)(r >> 16);
}

// ---------------------------------------------------------------------------
// prep_hist: blocks 0..63   -> W split/transpose (LDS transpose, coalesced)
//            blocks 64..319 -> bucket histogram (bq/bp pre-zeroed by memset)
// ---------------------------------------------------------------------------
__global__ __launch_bounds__(256) void prep_hist(
    const float* W0, const float* W1, const float* W2, const float* W3,
    const float* W4, const float* W5, const float* W6, const float* W7,
    unsigned short* __restrict__ wt,
    const int* __restrict__ dst_pv, const int* __restrict__ dst_vp, int E,
    int shq, int shp, int* __restrict__ bq, int* __restrict__ bp) {
    int blk = blockIdx.x;
    int tid = threadIdx.x;
    if (blk < 64) {
        int m = blk >> 3;
        int c0 = (blk & 7) * 16;
        const float* W;
        switch (m) {
            case 0: W = W0; break; case 1: W = W1; break;
            case 2: W = W2; break; case 3: W = W3; break;
            case 4: W = W4; break; case 5: W = W5; break;
            case 6: W = W6; break; default: W = W7; break;
        }
        unsigned short* hi = wt + (size_t)m * 32768;
        unsigned short* lo = hi + 16384;

        __shared__ unsigned short his[16][136];
        __shared__ unsigned short los[16][136];
        int cc = tid & 15;
        int kk = tid >> 4;
        #pragma unroll
        for (int g = 0; g < 8; ++g) {
            int k = g * 16 + kk;
            float x = W[k * 128 + c0 + cc];
            unsigned short h = f2bf(x);
            union { float f; unsigned u; } hv; hv.u = ((unsigned)h) << 16;
            his[cc][k] = h;
            los[cc][k] = f2bf(x - hv.f);
        }
        __syncthreads();
        int cidx = tid >> 4;
        int k8   = (tid & 15) * 8;
        int c = c0 + cidx;
        uint4 vh, vl;
        #pragma unroll
        for (int j = 0; j < 4; ++j) {
            ((unsigned*)&vh)[j] = *(const unsigned*)&his[cidx][k8 + j * 2];
            ((unsigned*)&vl)[j] = *(const unsigned*)&los[cidx][k8 + j * 2];
        }
        *(uint4*)(hi + (size_t)c * 128 + k8) = vh;
        *(uint4*)(lo + (size_t)c * 128 + k8) = vl;
    } else {
        __shared__ int hq[NBT], hp[NBT];
        if (tid < NBT) { hq[tid] = 0; hp[tid] = 0; }
        __syncthreads();
        for (int e = (blk - 64) * 256 + tid; e < E; e += 256 * 256) {
            atomicAdd(&hq[dst_pv[e] >> shq], 1);
            atomicAdd(&hp[dst_vp[e] >> shp], 1);
        }
        __syncthreads();
        if (tid < NBT) {
            if (hq[tid]) atomicAdd(&bq[tid], hq[tid]);
            if (hp[tid]) atomicAdd(&bp[tid], hp[tid]);
        }
    }
}

__global__ __launch_bounds__(128) void bscan(int* __restrict__ bq, int nbq,
                                             int* __restrict__ bp, int nbp,
                                             int* __restrict__ curq, int* __restrict__ curp,
                                             int* __restrict__ rp_q, int nq,
                                             int* __restrict__ rp_p, int np, int E) {
    int wid = threadIdx.x >> 6, lane = threadIdx.x & 63;
    int* seg = wid ? bp : bq;
    int* cur = wid ? curp : curq;
    int nseg = wid ? nbp : nbq;
    int carry = 0;
    for (int base = 0; base < nseg; base += 64) {
        int i = base + lane;
        int v = (i < nseg) ? seg[i] : 0;
        int inc = v;
        #pragma unroll
        for (int off = 1; off < 64; off <<= 1) {
            int t = __shfl_up(inc, off, 64);
            if (lane >= off) inc += t;
        }
        if (i < nseg) { int ex = carry + inc - v; seg[i] = ex; cur[i] = ex; }
        carry += __shfl(inc, 63, 64);
    }
    if (lane == 0) { if (wid == 0) rp_q[nq] = E; else rp_p[np] = E; }
}

// Block-batched scatter of packed (src<<sh | local_dst) into bucket order.
__global__ __launch_bounds__(256) void bscatter(const int* __restrict__ src_pv,
                                                const int* __restrict__ dst_pv,
                                                const int* __restrict__ src_vp,
                                                const int* __restrict__ dst_vp, int E,
                                                int* __restrict__ curq, int shq,
                                                int* __restrict__ curp, int shp,
                                                unsigned* __restrict__ pk_q,
                                                unsigned* __restrict__ pk_p) {
    __shared__ int cq[NBT], baq[NBT], wq[NBT];
    __shared__ int cp_[NBT], bap[NBT], wp_[NBT];
    int tid = threadIdx.x;
    int nblk = gridDim.x;
    int chunk = (E + nblk - 1) / nblk;
    int lo = blockIdx.x * chunk;
    int hi = min(lo + chunk, E);
    unsigned mkq = (1u << shq) - 1, mkp = (1u << shp) - 1;
    if (tid < NBT) { cq[tid] = 0; cp_[tid] = 0; }
    __syncthreads();
    for (int e = lo + tid; e < hi; e += 256) {
        atomicAdd(&cq[dst_pv[e] >> shq], 1);
        atomicAdd(&cp_[dst_vp[e] >> shp], 1);
    }
    __syncthreads();
    if (tid < NBT) {
        baq[tid] = cq[tid]  ? atomicAdd(&curq[tid], cq[tid])  : 0; wq[tid]  = 0;
        bap[tid] = cp_[tid] ? atomicAdd(&curp[tid], cp_[tid]) : 0; wp_[tid] = 0;
    }
    __syncthreads();
    for (int e = lo + tid; e < hi; e += 256) {
        int d = dst_pv[e]; int b = d >> shq;
        int off = atomicAdd(&wq[b], 1);
        pk_q[baq[b] + off] = ((unsigned)src_pv[e] << shq) | ((unsigned)d & mkq);
        d = dst_vp[e]; b = d >> shp;
        off = atomicAdd(&wp_[b], 1);
        pk_p[bap[b] + off] = ((unsigned)src_vp[e] << shp) | ((unsigned)d & mkp);
    }
}

// Per-bucket local CSR from packed entries.
__global__ __launch_bounds__(256) void bcsr(const unsigned* __restrict__ pk_q,
                                            const unsigned* __restrict__ pk_p,
                                            const int* __restrict__ bbq, int nbq,
                                            const int* __restrict__ bbp, int nbp,
                                            int* __restrict__ rp_q, int nq, int shq,
                                            int* __restrict__ rp_p, int np, int shp,
                                            int* __restrict__ col_q, int* __restrict__ col_p,
                                            int E) {
    int b = blockIdx.x;
    const unsigned* pk; const int* bb; int* rp; int* colg; int nb, n, sh;
    if (b < nbq) { pk = pk_q; bb = bbq; rp = rp_q; colg = col_q; nb = nbq; n = nq; sh = shq; }
    else { b -= nbq; pk = pk_p; bb = bbp; rp = rp_p; colg = col_p; nb = nbp; n = np; sh = shp; }
    int base = bb[b];
    int next = (b + 1 < nb) ? bb[b + 1] : E;
    int cnt = next - base;
    int dlo = b << sh;
    int dn  = min(1 << sh, n - dlo);
    unsigned mask = (1u << sh) - 1;

    __shared__ int deg[DNMAX];
    __shared__ int cur[DNMAX];
    __shared__ int wsum[4];
    int tid = threadIdx.x, lane = tid & 63, wid = tid >> 6;

    for (int i = tid; i < dn; i += 256) deg[i] = 0;
    __syncthreads();
    for (int i = tid; i < cnt; i += 256)
        atomicAdd(&deg[pk[base + i] & mask], 1);
    __syncthreads();

    int t2 = tid * 2;
    int d0 = (t2 < dn) ? deg[t2] : 0;
    int d1 = (t2 + 1 < dn) ? deg[t2 + 1] : 0;
    int s = d0 + d1;
    int inc = s;
    #pragma unroll
    for (int off = 1; off < 64; off <<= 1) {
        int t = __shfl_up(inc, off, 64);
        if (lane >= off) inc += t;
    }
    if (lane == 63) wsum[wid] = inc;
    __syncthreads();
    int wpre = 0;
    for (int w2 = 0; w2 < wid; ++w2) wpre += wsum[w2];
    int ex = wpre + inc - s;
    if (t2 < dn)     { cur[t2] = ex;           rp[dlo + t2] = base + ex; }
    if (t2 + 1 < dn) { cur[t2 + 1] = ex + d0;  rp[dlo + t2 + 1] = base + ex + d0; }
    __syncthreads();

    for (int i = tid; i < cnt; i += 256) {
        unsigned v = pk[base + i];
        int off = atomicAdd(&cur[v & mask], 1);
        colg[base + off] = (int)(v >> sh);
    }
}

// ---------------------------------------------------------------------------
// Persistent tiled gather-mean, f32 source (layer 0). Lane = sub(2b) x ch(4b):
// per edge, 16 lanes read 2 float4 = 512B row; 4 edges per instruction slot.
// ---------------------------------------------------------------------------
__global__ __launch_bounds__(256) void agg_l0(
    const int* __restrict__ rp_q, const int* __restrict__ col_q,
    const float* __restrict__ srcq, unsigned short* __restrict__ outq, int nq,
    const int* __restrict__ rp_p, const int* __restrict__ col_p,
    const float* __restrict__ srcp, unsigned short* __restrict__ outp, int np,
    int ntq, int ntot) {
    __shared__ int rps[GT + 1];
    __shared__ int cols[GCAP];

    int tid = threadIdx.x;
    int wid = tid >> 6, lane = tid & 63;
    int sub = lane >> 4;
    int ch  = lane & 15;

    for (int tile = blockIdx.x; tile < ntot; tile += gridDim.x) {
        const int* rp; const int* col; const float* src; unsigned short* out; int n, d0;
        if (tile < ntq) { rp = rp_q; col = col_q; src = srcq; out = outq; n = nq; d0 = tile * GT; }
        else { rp = rp_p; col = col_p; src = srcp; out = outp; n = np; d0 = (tile - ntq) * GT; }

        int nrow = min(GT, n - d0);
        if (tid <= nrow) rps[tid] = rp[d0 + tid];
        __syncthreads();
        int beg0 = rps[0];
        int cnt = rps[nrow] - beg0;
        bool useLds = cnt <= GCAP;
        if (useLds)
            for (int i = tid; i < cnt; i += 256) cols[i] = col[beg0 + i];
        __syncthreads();

        for (int r = wid; r < nrow; r += 4) {
            int beg = rps[r], end = rps[r + 1];
            float a0 = 0.f, a1 = 0.f, a2 = 0.f, a3 = 0.f;
            float a4 = 0.f, a5 = 0.f, a6 = 0.f, a7 = 0.f;
            for (int i = beg; i < end; i += 8) {
                float4 v[2][2]; bool act[2];
                #pragma unroll
                for (int h2 = 0; h2 < 2; ++h2) {
                    int j = i + h2 * 4 + sub;
                    act[h2] = j < end;
                    if (act[h2]) {
                        int s = useLds ? cols[j - beg0] : col[j];
                        const float* row = src + (size_t)s * D + ch * 8;
                        v[h2][0] = ((const float4*)row)[0];
                        v[h2][1] = ((const float4*)row)[1];
                    }
                }
                #pragma unroll
                for (int h2 = 0; h2 < 2; ++h2) {
                    if (act[h2]) {
                        a0 += v[h2][0].x; a1 += v[h2][0].y;
                        a2 += v[h2][0].z; a3 += v[h2][0].w;
                        a4 += v[h2][1].x; a5 += v[h2][1].y;
                        a6 += v[h2][1].z; a7 += v[h2][1].w;
                    }
                }
            }
            #pragma unroll
            for (int off = 16; off <= 32; off <<= 1) {
                a0 += __shfl_xor(a0, off); a1 += __shfl_xor(a1, off);
                a2 += __shfl_xor(a2, off); a3 += __shfl_xor(a3, off);
                a4 += __shfl_xor(a4, off); a5 += __shfl_xor(a5, off);
                a6 += __shfl_xor(a6, off); a7 += __shfl_xor(a7, off);
            }
            int deg = end - beg;
            float inv = (deg > 0) ? 1.0f / (float)deg : 0.f;
            if (sub == 0) {
                uint4 o;
                o.x = (unsigned)f2bf(a0 * inv) | ((unsigned)f2bf(a1 * inv) << 16);
                o.y = (unsigned)f2bf(a2 * inv) | ((unsigned)f2bf(a3 * inv) << 16);
                o.z = (unsigned)f2bf(a4 * inv) | ((unsigned)f2bf(a5 * inv) << 16);
                o.w = (unsigned)f2bf(a6 * inv) | ((unsigned)f2bf(a7 * inv) << 16);
                *(uint4*)(out + (size_t)(d0 + r) * D + ch * 8) = o;
            }
        }
        __syncthreads();   // protect rps/cols before next tile
    }
}

// ---------------------------------------------------------------------------
// Persistent tiled gather-mean, bf16 source (layer 1). Verified R9 structure.
// ---------------------------------------------------------------------------
__global__ __launch_bounds__(256) void agg_l1(
    const int* __restrict__ rp_q, const int* __restrict__ col_q,
    const unsigned short* __restrict__ srcq, unsigned short* __restrict__ outq, int nq,
    const int* __restrict__ rp_p, const int* __restrict__ col_p,
    const unsigned short* __restrict__ srcp, unsigned short* __restrict__ outp, int np,
    int ntq, int ntot) {
    __shared__ int rps[GT + 1];
    __shared__ int cols[GCAP];

    int tid = threadIdx.x;
    int wid = tid >> 6, lane = tid & 63;
    int sub = lane >> 4;
    int ch  = lane & 15;

    for (int tile = blockIdx.x; tile < ntot; tile += gridDim.x) {
        const int* rp; const int* col; const unsigned short* src; unsigned short* out; int n, d0;
        if (tile < ntq) { rp = rp_q; col = col_q; src = srcq; out = outq; n = nq; d0 = tile * GT; }
        else { rp = rp_p; col = col_p; src = srcp; out = outp; n = np; d0 = (tile - ntq) * GT; }

        int nrow = min(GT, n - d0);
        if (tid <= nrow) rps[tid] = rp[d0 + tid];
        __syncthreads();
        int beg0 = rps[0];
        int cnt = rps[nrow] - beg0;
        bool useLds = cnt <= GCAP;
        if (useLds)
            for (int i = tid; i < cnt; i += 256) cols[i] = col[beg0 + i];
        __syncthreads();

        for (int r = wid; r < nrow; r += 4) {
            int beg = rps[r], end = rps[r + 1];
            float a0 = 0.f, a1 = 0.f, a2 = 0.f, a3 = 0.f;
            float a4 = 0.f, a5 = 0.f, a6 = 0.f, a7 = 0.f;
            for (int i = beg; i < end; i += 16) {
                uint4 v[4]; bool act[4];
                #pragma unroll
                for (int h2 = 0; h2 < 4; ++h2) {
                    int j = i + h2 * 4 + sub;
                    act[h2] = j < end;
                    if (act[h2]) {
                        int s = useLds ? cols[j - beg0] : col[j];
                        v[h2] = *(const uint4*)(src + (size_t)s * D + ch * 8);
                    }
                }
                #pragma unroll
                for (int h2 = 0; h2 < 4; ++h2) {
                    if (act[h2]) {
                        union { unsigned u; float f; } t;
                        t.u = v[h2].x << 16;         a0 += t.f;
                        t.u = v[h2].x & 0xffff0000u; a1 += t.f;
                        t.u = v[h2].y << 16;         a2 += t.f;
                        t.u = v[h2].y & 0xffff0000u; a3 += t.f;
                        t.u = v[h2].z << 16;         a4 += t.f;
                        t.u = v[h2].z & 0xffff0000u; a5 += t.f;
                        t.u = v[h2].w << 16;         a6 += t.f;
                        t.u = v[h2].w & 0xffff0000u; a7 += t.f;
                    }
                }
            }
            #pragma unroll
            for (int off = 16; off <= 32; off <<= 1) {
                a0 += __shfl_xor(a0, off); a1 += __shfl_xor(a1, off);
                a2 += __shfl_xor(a2, off); a3 += __shfl_xor(a3, off);
                a4 += __shfl_xor(a4, off); a5 += __shfl_xor(a5, off);
                a6 += __shfl_xor(a6, off); a7 += __shfl_xor(a7, off);
            }
            int deg = end - beg;
            float inv = (deg > 0) ? 1.0f / (float)deg : 0.f;
            if (sub == 0) {
                uint4 o;
                o.x = (unsigned)f2bf(a0 * inv) | ((unsigned)f2bf(a1 * inv) << 16);
                o.y = (unsigned)f2bf(a2 * inv) | ((unsigned)f2bf(a3 * inv) << 16);
                o.z = (unsigned)f2bf(a4 * inv) | ((unsigned)f2bf(a5 * inv) << 16);
                o.w = (unsigned)f2bf(a6 * inv) | ((unsigned)f2bf(a7 * inv) << 16);
                *(uint4*)(out + (size_t)(d0 + r) * D + ch * 8) = o;
            }
        }
        __syncthreads();
    }
}

// ---------------------------------------------------------------------------
// MFMA dual GEMM body (all-bf16 A, hi/lo split W, 2 MFMAs/k-step)
// A2F32: A2 is f32, converted to bf16 inline during staging (layer 0).
// WF32: write f32 out. WHB: write bf16 hb.
// ---------------------------------------------------------------------------
struct GemmSide {
    const unsigned short* A1;
    const unsigned short* A2;    // bf16 A2 (layer 1)
    const float* A2f;            // f32 A2 (layer 0)
    const unsigned short* Wt1;
    const unsigned short* Wt2;
    const float* bias;
    float* out;
    unsigned short* hb;
    int n;
};

template <bool RELU, bool WF32, bool WHB, bool A2F32>
__device__ __forceinline__ void gemm_body(const GemmSide& S, int bidx) {
    __shared__ unsigned short As[128][PAD];
    __shared__ unsigned short Ws_hi[128][PAD];
    __shared__ unsigned short Ws_lo[128][PAD];

    const int tid  = threadIdx.x;
    const int lane = tid & 63;
    const int w    = tid >> 6;
    const int m0   = bidx * 128;
    const int n    = S.n;

    f32x4 acc[2][8];
    #pragma unroll
    for (int i = 0; i < 2; ++i)
        #pragma unroll
        for (int j = 0; j < 8; ++j) acc[i][j] = (f32x4)0.f;

    const int srow  = tid >> 1;          // 0..127
    const int skoff = (tid & 1) * 16;    // 0 or 16 (16 bf16 = two uint4)

    for (int ks = 0; ks < 8; ++ks) {
        const int half = ks >> 2;
        const int kb   = (ks & 3) * 32;
        const unsigned short* Wt = half ? S.Wt2 : S.Wt1;

        {
            int grow = m0 + srow;
            if (grow >= n) grow = n - 1;
            if (A2F32 && half) {
                const float* ap = S.A2f + (size_t)grow * D + kb + skoff;
                float4 u0 = ((const float4*)ap)[0];
                float4 u1 = ((const float4*)ap)[1];
                float4 u2 = ((const float4*)ap)[2];
                float4 u3 = ((const float4*)ap)[3];
                uint4 o0, o1;
                o0.x = (unsigned)f2bf(u0.x) | ((unsigned)f2bf(u0.y) << 16);
                o0.y = (unsigned)f2bf(u0.z) | ((unsigned)f2bf(u0.w) << 16);
                o0.z = (unsigned)f2bf(u1.x) | ((unsigned)f2bf(u1.y) << 16);
                o0.w = (unsigned)f2bf(u1.z) | ((unsigned)f2bf(u1.w) << 16);
                o1.x = (unsigned)f2bf(u2.x) | ((unsigned)f2bf(u2.y) << 16);
                o1.y = (unsigned)f2bf(u2.z) | ((unsigned)f2bf(u2.w) << 16);
                o1.z = (unsigned)f2bf(u3.x) | ((unsigned)f2bf(u3.y) << 16);
                o1.w = (unsigned)f2bf(u3.z) | ((unsigned)f2bf(u3.w) << 16);
                ((uint4*)&As[srow][skoff])[0] = o0;
                ((uint4*)&As[srow][skoff])[1] = o1;
            } else {
                const unsigned short* A = half ? S.A2 : S.A1;
                const uint4* pa = (const uint4*)(A + (size_t)grow * D + kb + skoff);
                ((uint4*)&As[srow][skoff])[0] = pa[0];
                ((uint4*)&As[srow][skoff])[1] = pa[1];
            }
        }
        {
            const uint4* ph = (const uint4*)(Wt + (size_t)srow * D + kb + skoff);
            ((uint4*)&Ws_hi[srow][skoff])[0] = ph[0];
            ((uint4*)&Ws_hi[srow][skoff])[1] = ph[1];
            const uint4* pl = (const uint4*)(Wt + 16384 + (size_t)srow * D + kb + skoff);
            ((uint4*)&Ws_lo[srow][skoff])[0] = pl[0];
            ((uint4*)&Ws_lo[srow][skoff])[1] = pl[1];
        }
        __syncthreads();

        const int r0 = w * 32;
        const int k8 = (lane >> 4) * 8;
        const int li = lane & 15;

        short8 ah[2];
        #pragma unroll
        for (int m = 0; m < 2; ++m)
            ah[m] = *(const short8*)&As[r0 + m * 16 + li][k8];
        #pragma unroll
        for (int nb = 0; nb < 8; ++nb) {
            int cc = nb * 16 + li;
            short8 bh = *(const short8*)&Ws_hi[cc][k8];
            short8 bl = *(const short8*)&Ws_lo[cc][k8];
            #pragma unroll
            for (int m = 0; m < 2; ++m) {
                acc[m][nb] = __builtin_amdgcn_mfma_f32_16x16x32_bf16(ah[m], bh, acc[m][nb], 0, 0, 0);
                acc[m][nb] = __builtin_amdgcn_mfma_f32_16x16x32_bf16(ah[m], bl, acc[m][nb], 0, 0, 0);
            }
        }
        __syncthreads();
    }

    const int li = lane & 15;
    const int rq = (lane >> 4) * 4;
    float bv[8];
    #pragma unroll
    for (int nb = 0; nb < 8; ++nb) bv[nb] = S.bias[nb * 16 + li];

    #pragma unroll
    for (int m = 0; m < 2; ++m) {
        #pragma unroll
        for (int nb = 0; nb < 8; ++nb) {
            #pragma unroll
            for (int r = 0; r < 4; ++r) {
                int R = m0 + w * 32 + m * 16 + rq + r;
                if (R < n) {
                    int C = nb * 16 + li;
                    float v = acc[m][nb][r] + bv[nb];
                    if (RELU) v = fmaxf(v, 0.f);
                    if (WF32) S.out[(size_t)R * D + C] = v;
                    if (WHB)  S.hb[(size_t)R * D + C] = f2bf(v);
                }
            }
        }
    }
}

template <bool RELU, bool WF32, bool WHB, bool A2F32>
__global__ __launch_bounds__(256) void gemm_both(GemmSide Sq, GemmSide Sp, int mq) {
    if ((int)blockIdx.x < mq) gemm_body<RELU, WF32, WHB, A2F32>(Sq, blockIdx.x);
    else                      gemm_body<RELU, WF32, WHB, A2F32>(Sp, blockIdx.x - mq);
}

// ---------------------------------------------------------------------------
extern "C" void kernel_launch(void* const* d_in, const int* in_sizes, int n_in,
                              void* d_out, int out_size, void* d_ws, size_t ws_size,
                              hipStream_t stream) {
    const float* x_p = (const float*)d_in[0];
    const float* x_q = (const float*)d_in[1];
    const int* src_pv = (const int*)d_in[2];
    const int* dst_pv = (const int*)d_in[3];
    const int* src_vp = (const int*)d_in[4];
    const int* dst_vp = (const int*)d_in[5];
    const float* Wl_pv0 = (const float*)d_in[6];
    const float* Wr_pv0 = (const float*)d_in[7];
    const float* b_pv0  = (const float*)d_in[8];
    const float* Wl_vp0 = (const float*)d_in[9];
    const float* Wr_vp0 = (const float*)d_in[10];
    const float* b_vp0  = (const float*)d_in[11];
    const float* Wl_pv1 = (const float*)d_in[12];
    const float* Wr_pv1 = (const float*)d_in[13];
    const float* b_pv1  = (const float*)d_in[14];
    const float* Wl_vp1 = (const float*)d_in[15];
    const float* Wr_vp1 = (const float*)d_in[16];
    const float* b_vp1  = (const float*)d_in[17];

    const int NP = in_sizes[0] / D;
    const int NQ = in_sizes[1] / D;
    const int E  = in_sizes[2];

    float* out_p = (float*)d_out;
    float* out_q = out_p + (size_t)NP * D;

    int shq = 6; while ((((NQ - 1) >> shq) + 1) > NBT) ++shq;
    int shp = 6; while ((((NP - 1) >> shp) + 1) > NBT) ++shp;
    int nbq = ((NQ - 1) >> shq) + 1;
    int nbp = ((NP - 1) >> shp) + 1;

    // workspace layout
    char* ws = (char*)d_ws;
    int* rp_q  = (int*)ws;
    int* rp_p  = rp_q + (NQ + 1);
    int* col_q = rp_p + (NP + 1);
    int* col_p = col_q + E;
    int* bq    = col_p + E;
    int* bp    = bq + NBT;
    int* curq  = bp + NBT;
    int* curp  = curq + NBT;
    size_t int_bytes = ((size_t)(NQ + 1) + (NP + 1) + 2 * (size_t)E + 4 * NBT) * sizeof(int);
    int_bytes = (int_bytes + 511) & ~(size_t)511;
    unsigned short* wt = (unsigned short*)(ws + int_bytes);
    size_t wt_bytes = ((size_t)8 * 32768 * sizeof(unsigned short) + 511) & ~(size_t)511;
    unsigned short* hb_p = (unsigned short*)(ws + int_bytes + wt_bytes);  // NP*128 (h1 bf16)
    unsigned short* hb_q = hb_p + (size_t)NP * D;                          // NQ*128
    unsigned short* aggb_q = hb_q + (size_t)NQ * D;                        // NQ*128
    unsigned short* aggb_p = aggb_q + (size_t)NQ * D;                      // NP*128
    unsigned* pk_q = (unsigned*)aggb_q;   // alias (dead before first agg write)
    unsigned* pk_p = pk_q + E;

    // --- prep (W split + hist; bq/bp zeroed first) ---
    hipMemsetAsync(bq, 0, 2 * NBT * sizeof(int), stream);
    prep_hist<<<320, 256, 0, stream>>>(Wl_pv0, Wr_pv0, Wl_vp0, Wr_vp0,
                                       Wl_pv1, Wr_pv1, Wl_vp1, Wr_vp1, wt,
                                       dst_pv, dst_vp, E, shq, shp, bq, bp);

    // --- CSR build ---
    bscan<<<1, 128, 0, stream>>>(bq, nbq, bp, nbp, curq, curp, rp_q, NQ, rp_p, NP, E);
    bscatter<<<512, 256, 0, stream>>>(src_pv, dst_pv, src_vp, dst_vp, E,
                                      curq, shq, curp, shp, pk_q, pk_p);
    bcsr<<<nbq + nbp, 256, 0, stream>>>(pk_q, pk_p, bq, nbq, bp, nbp,
                                        rp_q, NQ, shq, rp_p, NP, shp, col_q, col_p, E);

    int ntq = (NQ + GT - 1) / GT, ntp = (NP + GT - 1) / GT;
    int mq = (NQ + 127) / 128, mp = (NP + 127) / 128;

    GemmSide Sq0 = { aggb_q, nullptr, x_q, wt + 0 * 32768, wt + 1 * 32768, b_pv0, out_q, hb_q, NQ };
    GemmSide Sp0 = { aggb_p, nullptr, x_p, wt + 2 * 32768, wt + 3 * 32768, b_vp0, out_p, hb_p, NP };
    GemmSide Sq1 = { aggb_q, hb_q, nullptr, wt + 4 * 32768, wt + 5 * 32768, b_pv1, out_q, nullptr, NQ };
    GemmSide Sp1 = { aggb_p, hb_p, nullptr, wt + 6 * 32768, wt + 7 * 32768, b_vp1, out_p, nullptr, NP };

    // --- layer 0: gather from f32 x directly; gemm stages A2 from f32 inline ---
    agg_l0<<<2048, 256, 0, stream>>>(rp_q, col_q, x_p, aggb_q, NQ,
                                     rp_p, col_p, x_q, aggb_p, NP, ntq, ntq + ntp);
    gemm_both<true, false, true, true><<<mq + mp, 256, 0, stream>>>(Sq0, Sp0, mq);

    // --- layer 1 ---
    agg_l1<<<2048, 256, 0, stream>>>(rp_q, col_q, hb_p, aggb_q, NQ,
                                     rp_p, col_p, hb_q, aggb_p, NP, ntq, ntq + ntp);
    gemm_both<false, true, false, false><<<mq + mp, 256, 0, stream>>>(Sq1, Sp1, mq);
}

// Round 13
// 256.911 us; speedup vs baseline: 1.1848x; 1.1848x over previous
//
#include <hip/hip_runtime.h>

#define D 128
#define PAD 40
#define NBT 256      // max buckets per node type
#define DNMAX 512    // max dsts per bucket
#define GT 32        // dst rows per gather block
#define GCAP 4096    // staged col window cap (ints)

typedef __attribute__((ext_vector_type(8))) short short8;
typedef __attribute__((ext_vector_type(4))) float f32x4;

__device__ __forceinline__ unsigned short f2bf(float x) {
    union { float f; unsigned u; } v; v.f = x;
    unsigned r = v.u + 0x7fff + ((v.u >> 16) & 1);   // RNE
    return (unsigned short)(r >> 16);
}

// ---------------------------------------------------------------------------
// prep_hist: blocks 0..63   -> W split/transpose (LDS transpose, coalesced)
//            blocks 64..319 -> bucket histogram (bq/bp pre-zeroed by memset)
//            blocks 320..   -> f32->bf16 conversion of x_p, x_q
// ---------------------------------------------------------------------------
__global__ __launch_bounds__(256) void prep_hist(
    const float* W0, const float* W1, const float* W2, const float* W3,
    const float* W4, const float* W5, const float* W6, const float* W7,
    unsigned short* __restrict__ wt,
    const int* __restrict__ dst_pv, const int* __restrict__ dst_vp, int E,
    int shq, int shp, int* __restrict__ bq, int* __restrict__ bp,
    const float* __restrict__ xp, unsigned short* __restrict__ xbp, int np4,
    const float* __restrict__ xq, unsigned short* __restrict__ xbq, int nq4) {
    int blk = blockIdx.x;
    int tid = threadIdx.x;
    if (blk < 64) {
        int m = blk >> 3;
        int c0 = (blk & 7) * 16;
        const float* W;
        switch (m) {
            case 0: W = W0; break; case 1: W = W1; break;
            case 2: W = W2; break; case 3: W = W3; break;
            case 4: W = W4; break; case 5: W = W5; break;
            case 6: W = W6; break; default: W = W7; break;
        }
        unsigned short* hi = wt + (size_t)m * 32768;
        unsigned short* lo = hi + 16384;

        __shared__ unsigned short his[16][136];
        __shared__ unsigned short los[16][136];
        int cc = tid & 15;
        int kk = tid >> 4;
        #pragma unroll
        for (int g = 0; g < 8; ++g) {
            int k = g * 16 + kk;
            float x = W[k * 128 + c0 + cc];
            unsigned short h = f2bf(x);
            union { float f; unsigned u; } hv; hv.u = ((unsigned)h) << 16;
            his[cc][k] = h;
            los[cc][k] = f2bf(x - hv.f);
        }
        __syncthreads();
        int cidx = tid >> 4;
        int k8   = (tid & 15) * 8;
        int c = c0 + cidx;
        uint4 vh, vl;
        #pragma unroll
        for (int j = 0; j < 4; ++j) {
            ((unsigned*)&vh)[j] = *(const unsigned*)&his[cidx][k8 + j * 2];
            ((unsigned*)&vl)[j] = *(const unsigned*)&los[cidx][k8 + j * 2];
        }
        *(uint4*)(hi + (size_t)c * 128 + k8) = vh;
        *(uint4*)(lo + (size_t)c * 128 + k8) = vl;
    } else if (blk < 320) {
        __shared__ int hq[NBT], hp[NBT];
        if (tid < NBT) { hq[tid] = 0; hp[tid] = 0; }
        __syncthreads();
        for (int e = (blk - 64) * 256 + tid; e < E; e += 256 * 256) {
            atomicAdd(&hq[dst_pv[e] >> shq], 1);
            atomicAdd(&hp[dst_vp[e] >> shp], 1);
        }
        __syncthreads();
        if (tid < NBT) {
            if (hq[tid]) atomicAdd(&bq[tid], hq[tid]);
            if (hp[tid]) atomicAdd(&bp[tid], hp[tid]);
        }
    } else {
        int tot = np4 + nq4;
        int stride = (gridDim.x - 320) * 256;
        for (int g = (blk - 320) * 256 + tid; g < tot; g += stride) {
            const float* src; unsigned short* dst; int i;
            if (g < np4) { src = xp; dst = xbp; i = g; }
            else         { src = xq; dst = xbq; i = g - np4; }
            float4 v = ((const float4*)src)[i];
            ushort4 o;
            o.x = f2bf(v.x); o.y = f2bf(v.y); o.z = f2bf(v.z); o.w = f2bf(v.w);
            ((ushort4*)dst)[i] = o;
        }
    }
}

__global__ __launch_bounds__(128) void bscan(int* __restrict__ bq, int nbq,
                                             int* __restrict__ bp, int nbp,
                                             int* __restrict__ curq, int* __restrict__ curp,
                                             int* __restrict__ rp_q, int nq,
                                             int* __restrict__ rp_p, int np, int E) {
    int wid = threadIdx.x >> 6, lane = threadIdx.x & 63;
    int* seg = wid ? bp : bq;
    int* cur = wid ? curp : curq;
    int nseg = wid ? nbp : nbq;
    int carry = 0;
    for (int base = 0; base < nseg; base += 64) {
        int i = base + lane;
        int v = (i < nseg) ? seg[i] : 0;
        int inc = v;
        #pragma unroll
        for (int off = 1; off < 64; off <<= 1) {
            int t = __shfl_up(inc, off, 64);
            if (lane >= off) inc += t;
        }
        if (i < nseg) { int ex = carry + inc - v; seg[i] = ex; cur[i] = ex; }
        carry += __shfl(inc, 63, 64);
    }
    if (lane == 0) { if (wid == 0) rp_q[nq] = E; else rp_p[np] = E; }
}

// Block-batched scatter of packed (src<<sh | local_dst) into bucket order.
__global__ __launch_bounds__(256) void bscatter(const int* __restrict__ src_pv,
                                                const int* __restrict__ dst_pv,
                                                const int* __restrict__ src_vp,
                                                const int* __restrict__ dst_vp, int E,
                                                int* __restrict__ curq, int shq,
                                                int* __restrict__ curp, int shp,
                                                unsigned* __restrict__ pk_q,
                                                unsigned* __restrict__ pk_p) {
    __shared__ int cq[NBT], baq[NBT], wq[NBT];
    __shared__ int cp_[NBT], bap[NBT], wp_[NBT];
    int tid = threadIdx.x;
    int nblk = gridDim.x;
    int chunk = (E + nblk - 1) / nblk;
    int lo = blockIdx.x * chunk;
    int hi = min(lo + chunk, E);
    unsigned mkq = (1u << shq) - 1, mkp = (1u << shp) - 1;
    if (tid < NBT) { cq[tid] = 0; cp_[tid] = 0; }
    __syncthreads();
    for (int e = lo + tid; e < hi; e += 256) {
        atomicAdd(&cq[dst_pv[e] >> shq], 1);
        atomicAdd(&cp_[dst_vp[e] >> shp], 1);
    }
    __syncthreads();
    if (tid < NBT) {
        baq[tid] = cq[tid]  ? atomicAdd(&curq[tid], cq[tid])  : 0; wq[tid]  = 0;
        bap[tid] = cp_[tid] ? atomicAdd(&curp[tid], cp_[tid]) : 0; wp_[tid] = 0;
    }
    __syncthreads();
    for (int e = lo + tid; e < hi; e += 256) {
        int d = dst_pv[e]; int b = d >> shq;
        int off = atomicAdd(&wq[b], 1);
        pk_q[baq[b] + off] = ((unsigned)src_pv[e] << shq) | ((unsigned)d & mkq);
        d = dst_vp[e]; b = d >> shp;
        off = atomicAdd(&wp_[b], 1);
        pk_p[bap[b] + off] = ((unsigned)src_vp[e] << shp) | ((unsigned)d & mkp);
    }
}

// Per-bucket local CSR from packed entries.
__global__ __launch_bounds__(256) void bcsr(const unsigned* __restrict__ pk_q,
                                            const unsigned* __restrict__ pk_p,
                                            const int* __restrict__ bbq, int nbq,
                                            const int* __restrict__ bbp, int nbp,
                                            int* __restrict__ rp_q, int nq, int shq,
                                            int* __restrict__ rp_p, int np, int shp,
                                            int* __restrict__ col_q, int* __restrict__ col_p,
                                            int E) {
    int b = blockIdx.x;
    const unsigned* pk; const int* bb; int* rp; int* colg; int nb, n, sh;
    if (b < nbq) { pk = pk_q; bb = bbq; rp = rp_q; colg = col_q; nb = nbq; n = nq; sh = shq; }
    else { b -= nbq; pk = pk_p; bb = bbp; rp = rp_p; colg = col_p; nb = nbp; n = np; sh = shp; }
    int base = bb[b];
    int next = (b + 1 < nb) ? bb[b + 1] : E;
    int cnt = next - base;
    int dlo = b << sh;
    int dn  = min(1 << sh, n - dlo);
    unsigned mask = (1u << sh) - 1;

    __shared__ int deg[DNMAX];
    __shared__ int cur[DNMAX];
    __shared__ int wsum[4];
    int tid = threadIdx.x, lane = tid & 63, wid = tid >> 6;

    for (int i = tid; i < dn; i += 256) deg[i] = 0;
    __syncthreads();
    for (int i = tid; i < cnt; i += 256)
        atomicAdd(&deg[pk[base + i] & mask], 1);
    __syncthreads();

    int t2 = tid * 2;
    int d0 = (t2 < dn) ? deg[t2] : 0;
    int d1 = (t2 + 1 < dn) ? deg[t2 + 1] : 0;
    int s = d0 + d1;
    int inc = s;
    #pragma unroll
    for (int off = 1; off < 64; off <<= 1) {
        int t = __shfl_up(inc, off, 64);
        if (lane >= off) inc += t;
    }
    if (lane == 63) wsum[wid] = inc;
    __syncthreads();
    int wpre = 0;
    for (int w2 = 0; w2 < wid; ++w2) wpre += wsum[w2];
    int ex = wpre + inc - s;
    if (t2 < dn)     { cur[t2] = ex;           rp[dlo + t2] = base + ex; }
    if (t2 + 1 < dn) { cur[t2 + 1] = ex + d0;  rp[dlo + t2 + 1] = base + ex + d0; }
    __syncthreads();

    for (int i = tid; i < cnt; i += 256) {
        unsigned v = pk[base + i];
        int off = atomicAdd(&cur[v & mask], 1);
        colg[base + off] = (int)(v >> sh);
    }
}

// ---------------------------------------------------------------------------
// Tiled gather-mean, bf16 rows, 4 loads in flight (verified R10/R11)
// ---------------------------------------------------------------------------
__global__ __launch_bounds__(256) void agg_all(
    const int* __restrict__ rp_q, const int* __restrict__ col_q,
    const unsigned short* __restrict__ srcq, unsigned short* __restrict__ outq, int nq,
    const int* __restrict__ rp_p, const int* __restrict__ col_p,
    const unsigned short* __restrict__ srcp, unsigned short* __restrict__ outp, int np,
    int ntq) {
    __shared__ int rps[GT + 1];
    __shared__ int cols[GCAP];

    int blk = blockIdx.x;
    const int* rp; const int* col; const unsigned short* src; unsigned short* out; int n, d0;
    if (blk < ntq) { rp = rp_q; col = col_q; src = srcq; out = outq; n = nq; d0 = blk * GT; }
    else { rp = rp_p; col = col_p; src = srcp; out = outp; n = np; d0 = (blk - ntq) * GT; }

    int tid = threadIdx.x;
    int nrow = min(GT, n - d0);
    if (tid <= nrow) rps[tid] = rp[d0 + tid];
    __syncthreads();
    int beg0 = rps[0];
    int cnt = rps[nrow] - beg0;
    bool useLds = cnt <= GCAP;
    if (useLds)
        for (int i = tid; i < cnt; i += 256) cols[i] = col[beg0 + i];
    __syncthreads();

    int wid = tid >> 6, lane = tid & 63;
    int sub = lane >> 4;
    int ch  = lane & 15;

    for (int r = wid; r < nrow; r += 4) {
        int beg = rps[r], end = rps[r + 1];
        float a0 = 0.f, a1 = 0.f, a2 = 0.f, a3 = 0.f;
        float a4 = 0.f, a5 = 0.f, a6 = 0.f, a7 = 0.f;
        for (int i = beg; i < end; i += 16) {
            uint4 v[4]; bool act[4];
            #pragma unroll
            for (int h2 = 0; h2 < 4; ++h2) {
                int j = i + h2 * 4 + sub;
                act[h2] = j < end;
                if (act[h2]) {
                    int s = useLds ? cols[j - beg0] : col[j];
                    v[h2] = *(const uint4*)(src + (size_t)s * D + ch * 8);
                }
            }
            #pragma unroll
            for (int h2 = 0; h2 < 4; ++h2) {
                if (act[h2]) {
                    union { unsigned u; float f; } t;
                    t.u = v[h2].x << 16;         a0 += t.f;
                    t.u = v[h2].x & 0xffff0000u; a1 += t.f;
                    t.u = v[h2].y << 16;         a2 += t.f;
                    t.u = v[h2].y & 0xffff0000u; a3 += t.f;
                    t.u = v[h2].z << 16;         a4 += t.f;
                    t.u = v[h2].z & 0xffff0000u; a5 += t.f;
                    t.u = v[h2].w << 16;         a6 += t.f;
                    t.u = v[h2].w & 0xffff0000u; a7 += t.f;
                }
            }
        }
        #pragma unroll
        for (int off = 16; off <= 32; off <<= 1) {
            a0 += __shfl_xor(a0, off); a1 += __shfl_xor(a1, off);
            a2 += __shfl_xor(a2, off); a3 += __shfl_xor(a3, off);
            a4 += __shfl_xor(a4, off); a5 += __shfl_xor(a5, off);
            a6 += __shfl_xor(a6, off); a7 += __shfl_xor(a7, off);
        }
        int deg = end - beg;
        float inv = (deg > 0) ? 1.0f / (float)deg : 0.f;
        if (sub == 0) {
            uint4 o;
            o.x = (unsigned)f2bf(a0 * inv) | ((unsigned)f2bf(a1 * inv) << 16);
            o.y = (unsigned)f2bf(a2 * inv) | ((unsigned)f2bf(a3 * inv) << 16);
            o.z = (unsigned)f2bf(a4 * inv) | ((unsigned)f2bf(a5 * inv) << 16);
            o.w = (unsigned)f2bf(a6 * inv) | ((unsigned)f2bf(a7 * inv) << 16);
            *(uint4*)(out + (size_t)(d0 + r) * D + ch * 8) = o;
        }
    }
}

// ---------------------------------------------------------------------------
// MFMA dual GEMM body (all-bf16 A, hi/lo split W, 2 MFMAs/k-step)
// WF32: write f32 out (non-temporal — never re-read). WHB: write bf16 hb.
// ---------------------------------------------------------------------------
struct GemmSide {
    const unsigned short* A1;
    const unsigned short* A2;
    const unsigned short* Wt1;
    const unsigned short* Wt2;
    const float* bias;
    float* out;
    unsigned short* hb;
    int n;
};

template <bool RELU, bool WF32, bool WHB>
__device__ __forceinline__ void gemm_body(const GemmSide& S, int bidx) {
    __shared__ unsigned short As[128][PAD];
    __shared__ unsigned short Ws_hi[128][PAD];
    __shared__ unsigned short Ws_lo[128][PAD];

    const int tid  = threadIdx.x;
    const int lane = tid & 63;
    const int w    = tid >> 6;
    const int m0   = bidx * 128;
    const int n    = S.n;

    f32x4 acc[2][8];
    #pragma unroll
    for (int i = 0; i < 2; ++i)
        #pragma unroll
        for (int j = 0; j < 8; ++j) acc[i][j] = (f32x4)0.f;

    const int srow  = tid >> 1;
    const int skoff = (tid & 1) * 16;

    for (int ks = 0; ks < 8; ++ks) {
        const int half = ks >> 2;
        const int kb   = (ks & 3) * 32;
        const unsigned short* A  = half ? S.A2 : S.A1;
        const unsigned short* Wt = half ? S.Wt2 : S.Wt1;

        {
            int grow = m0 + srow;
            if (grow >= n) grow = n - 1;
            const uint4* pa = (const uint4*)(A + (size_t)grow * D + kb + skoff);
            ((uint4*)&As[srow][skoff])[0] = pa[0];
            ((uint4*)&As[srow][skoff])[1] = pa[1];
        }
        {
            const uint4* ph = (const uint4*)(Wt + (size_t)srow * D + kb + skoff);
            ((uint4*)&Ws_hi[srow][skoff])[0] = ph[0];
            ((uint4*)&Ws_hi[srow][skoff])[1] = ph[1];
            const uint4* pl = (const uint4*)(Wt + 16384 + (size_t)srow * D + kb + skoff);
            ((uint4*)&Ws_lo[srow][skoff])[0] = pl[0];
            ((uint4*)&Ws_lo[srow][skoff])[1] = pl[1];
        }
        __syncthreads();

        const int r0 = w * 32;
        const int k8 = (lane >> 4) * 8;
        const int li = lane & 15;

        short8 ah[2];
        #pragma unroll
        for (int m = 0; m < 2; ++m)
            ah[m] = *(const short8*)&As[r0 + m * 16 + li][k8];
        #pragma unroll
        for (int nb = 0; nb < 8; ++nb) {
            int cc = nb * 16 + li;
            short8 bh = *(const short8*)&Ws_hi[cc][k8];
            short8 bl = *(const short8*)&Ws_lo[cc][k8];
            #pragma unroll
            for (int m = 0; m < 2; ++m) {
                acc[m][nb] = __builtin_amdgcn_mfma_f32_16x16x32_bf16(ah[m], bh, acc[m][nb], 0, 0, 0);
                acc[m][nb] = __builtin_amdgcn_mfma_f32_16x16x32_bf16(ah[m], bl, acc[m][nb], 0, 0, 0);
            }
        }
        __syncthreads();
    }

    const int li = lane & 15;
    const int rq = (lane >> 4) * 4;
    float bv[8];
    #pragma unroll
    for (int nb = 0; nb < 8; ++nb) bv[nb] = S.bias[nb * 16 + li];

    #pragma unroll
    for (int m = 0; m < 2; ++m) {
        #pragma unroll
        for (int nb = 0; nb < 8; ++nb) {
            #pragma unroll
            for (int r = 0; r < 4; ++r) {
                int R = m0 + w * 32 + m * 16 + rq + r;
                if (R < n) {
                    int C = nb * 16 + li;
                    float v = acc[m][nb][r] + bv[nb];
                    if (RELU) v = fmaxf(v, 0.f);
                    if (WF32) __builtin_nontemporal_store(v, &S.out[(size_t)R * D + C]);
                    if (WHB)  S.hb[(size_t)R * D + C] = f2bf(v);
                }
            }
        }
    }
}

template <bool RELU, bool WF32, bool WHB>
__global__ __launch_bounds__(256) void gemm_both(GemmSide Sq, GemmSide Sp, int mq) {
    if ((int)blockIdx.x < mq) gemm_body<RELU, WF32, WHB>(Sq, blockIdx.x);
    else                      gemm_body<RELU, WF32, WHB>(Sp, blockIdx.x - mq);
}

// ---------------------------------------------------------------------------
extern "C" void kernel_launch(void* const* d_in, const int* in_sizes, int n_in,
                              void* d_out, int out_size, void* d_ws, size_t ws_size,
                              hipStream_t stream) {
    const float* x_p = (const float*)d_in[0];
    const float* x_q = (const float*)d_in[1];
    const int* src_pv = (const int*)d_in[2];
    const int* dst_pv = (const int*)d_in[3];
    const int* src_vp = (const int*)d_in[4];
    const int* dst_vp = (const int*)d_in[5];
    const float* Wl_pv0 = (const float*)d_in[6];
    const float* Wr_pv0 = (const float*)d_in[7];
    const float* b_pv0  = (const float*)d_in[8];
    const float* Wl_vp0 = (const float*)d_in[9];
    const float* Wr_vp0 = (const float*)d_in[10];
    const float* b_vp0  = (const float*)d_in[11];
    const float* Wl_pv1 = (const float*)d_in[12];
    const float* Wr_pv1 = (const float*)d_in[13];
    const float* b_pv1  = (const float*)d_in[14];
    const float* Wl_vp1 = (const float*)d_in[15];
    const float* Wr_vp1 = (const float*)d_in[16];
    const float* b_vp1  = (const float*)d_in[17];

    const int NP = in_sizes[0] / D;
    const int NQ = in_sizes[1] / D;
    const int E  = in_sizes[2];

    float* out_p = (float*)d_out;
    float* out_q = out_p + (size_t)NP * D;

    int shq = 6; while ((((NQ - 1) >> shq) + 1) > NBT) ++shq;
    int shp = 6; while ((((NP - 1) >> shp) + 1) > NBT) ++shp;
    int nbq = ((NQ - 1) >> shq) + 1;
    int nbp = ((NP - 1) >> shp) + 1;

    // workspace layout
    char* ws = (char*)d_ws;
    int* rp_q  = (int*)ws;
    int* rp_p  = rp_q + (NQ + 1);
    int* col_q = rp_p + (NP + 1);
    int* col_p = col_q + E;
    int* bq    = col_p + E;
    int* bp    = bq + NBT;
    int* curq  = bp + NBT;
    int* curp  = curq + NBT;
    size_t int_bytes = ((size_t)(NQ + 1) + (NP + 1) + 2 * (size_t)E + 4 * NBT) * sizeof(int);
    int_bytes = (int_bytes + 511) & ~(size_t)511;
    unsigned short* wt = (unsigned short*)(ws + int_bytes);
    size_t wt_bytes = ((size_t)8 * 32768 * sizeof(unsigned short) + 511) & ~(size_t)511;
    unsigned short* xb_p = (unsigned short*)(ws + int_bytes + wt_bytes);  // NP*128
    unsigned short* xb_q = xb_p + (size_t)NP * D;                          // NQ*128
    unsigned short* hb_p = xb_p;   // alias (block-local in-place, see gemm)
    unsigned short* hb_q = xb_q;
    unsigned short* aggb_q = xb_q + (size_t)NQ * D;                        // NQ*128
    unsigned short* aggb_p = aggb_q + (size_t)NQ * D;                      // NP*128
    unsigned* pk_q = (unsigned*)aggb_q;   // alias (dead before first agg write)
    unsigned* pk_p = pk_q + E;

    // --- prep (W split, hist, x->bf16; bq/bp zeroed first) ---
    hipMemsetAsync(bq, 0, 2 * NBT * sizeof(int), stream);
    prep_hist<<<320 + 2048, 256, 0, stream>>>(Wl_pv0, Wr_pv0, Wl_vp0, Wr_vp0,
                                              Wl_pv1, Wr_pv1, Wl_vp1, Wr_vp1, wt,
                                              dst_pv, dst_vp, E, shq, shp, bq, bp,
                                              x_p, xb_p, NP * D / 4, x_q, xb_q, NQ * D / 4);

    // --- CSR build ---
    bscan<<<1, 128, 0, stream>>>(bq, nbq, bp, nbp, curq, curp, rp_q, NQ, rp_p, NP, E);
    bscatter<<<512, 256, 0, stream>>>(src_pv, dst_pv, src_vp, dst_vp, E,
                                      curq, shq, curp, shp, pk_q, pk_p);
    bcsr<<<nbq + nbp, 256, 0, stream>>>(pk_q, pk_p, bq, nbq, bp, nbp,
                                        rp_q, NQ, shq, rp_p, NP, shp, col_q, col_p, E);

    int ntq = (NQ + GT - 1) / GT, ntp = (NP + GT - 1) / GT;
    int mq = (NQ + 127) / 128, mp = (NP + 127) / 128;

    GemmSide Sq0 = { aggb_q, xb_q, wt + 0 * 32768, wt + 1 * 32768, b_pv0, out_q, hb_q, NQ };
    GemmSide Sp0 = { aggb_p, xb_p, wt + 2 * 32768, wt + 3 * 32768, b_vp0, out_p, hb_p, NP };
    GemmSide Sq1 = { aggb_q, hb_q, wt + 4 * 32768, wt + 5 * 32768, b_pv1, out_q, nullptr, NQ };
    GemmSide Sp1 = { aggb_p, hb_p, wt + 6 * 32768, wt + 7 * 32768, b_vp1, out_p, nullptr, NP };

    // --- layer 0 (f32 out stores dead; write bf16 h1 only) ---
    agg_all<<<ntq + ntp, 256, 0, stream>>>(rp_q, col_q, xb_p, aggb_q, NQ,
                                           rp_p, col_p, xb_q, aggb_p, NP, ntq);
    gemm_both<true, false, true><<<mq + mp, 256, 0, stream>>>(Sq0, Sp0, mq);

    // --- layer 1 ---
    agg_all<<<ntq + ntp, 256, 0, stream>>>(rp_q, col_q, hb_p, aggb_q, NQ,
                                           rp_p, col_p, hb_q, aggb_p, NP, ntq);
    gemm_both<false, true, false><<<mq + mp, 256, 0, stream>>>(Sq1, Sp1, mq);
}

// Round 14
// 256.236 us; speedup vs baseline: 1.1879x; 1.0026x over previous
//
#include <hip/hip_runtime.h>

#define D 128
#define PAD 40
#define NBT 256      // max buckets per node type
#define DNMAX 512    // max dsts per bucket
#define GT 32        // dst rows per gather block
#define GCAP 4096    // staged col window cap (ints)

typedef __attribute__((ext_vector_type(8))) short short8;
typedef __attribute__((ext_vector_type(4))) float f32x4;

__device__ __forceinline__ unsigned short f2bf(float x) {
    union { float f; unsigned u; } v; v.f = x;
    unsigned r = v.u + 0x7fff + ((v.u >> 16) & 1);   // RNE
    return (unsigned short)(r >> 16);
}

// ---------------------------------------------------------------------------
// prep_hist: blocks 0..63   -> W split/transpose (LDS transpose, coalesced)
//            blocks 64..319 -> bucket histogram (bq/bp pre-zeroed by memset)
// ---------------------------------------------------------------------------
__global__ __launch_bounds__(256) void prep_hist(
    const float* W0, const float* W1, const float* W2, const float* W3,
    const float* W4, const float* W5, const float* W6, const float* W7,
    unsigned short* __restrict__ wt,
    const int* __restrict__ dst_pv, const int* __restrict__ dst_vp, int E,
    int shq, int shp, int* __restrict__ bq, int* __restrict__ bp) {
    int blk = blockIdx.x;
    int tid = threadIdx.x;
    if (blk < 64) {
        int m = blk >> 3;
        int c0 = (blk & 7) * 16;
        const float* W;
        switch (m) {
            case 0: W = W0; break; case 1: W = W1; break;
            case 2: W = W2; break; case 3: W = W3; break;
            case 4: W = W4; break; case 5: W = W5; break;
            case 6: W = W6; break; default: W = W7; break;
        }
        unsigned short* hi = wt + (size_t)m * 32768;
        unsigned short* lo = hi + 16384;

        __shared__ unsigned short his[16][136];
        __shared__ unsigned short los[16][136];
        int cc = tid & 15;
        int kk = tid >> 4;
        #pragma unroll
        for (int g = 0; g < 8; ++g) {
            int k = g * 16 + kk;
            float x = W[k * 128 + c0 + cc];
            unsigned short h = f2bf(x);
            union { float f; unsigned u; } hv; hv.u = ((unsigned)h) << 16;
            his[cc][k] = h;
            los[cc][k] = f2bf(x - hv.f);
        }
        __syncthreads();
        int cidx = tid >> 4;
        int k8   = (tid & 15) * 8;
        int c = c0 + cidx;
        uint4 vh, vl;
        #pragma unroll
        for (int j = 0; j < 4; ++j) {
            ((unsigned*)&vh)[j] = *(const unsigned*)&his[cidx][k8 + j * 2];
            ((unsigned*)&vl)[j] = *(const unsigned*)&los[cidx][k8 + j * 2];
        }
        *(uint4*)(hi + (size_t)c * 128 + k8) = vh;
        *(uint4*)(lo + (size_t)c * 128 + k8) = vl;
    } else {
        __shared__ int hq[NBT], hp[NBT];
        if (tid < NBT) { hq[tid] = 0; hp[tid] = 0; }
        __syncthreads();
        for (int e = (blk - 64) * 256 + tid; e < E; e += 256 * 256) {
            atomicAdd(&hq[dst_pv[e] >> shq], 1);
            atomicAdd(&hp[dst_vp[e] >> shp], 1);
        }
        __syncthreads();
        if (tid < NBT) {
            if (hq[tid]) atomicAdd(&bq[tid], hq[tid]);
            if (hp[tid]) atomicAdd(&bp[tid], hp[tid]);
        }
    }
}

__global__ __launch_bounds__(128) void bscan(int* __restrict__ bq, int nbq,
                                             int* __restrict__ bp, int nbp,
                                             int* __restrict__ curq, int* __restrict__ curp,
                                             int* __restrict__ rp_q, int nq,
                                             int* __restrict__ rp_p, int np, int E) {
    int wid = threadIdx.x >> 6, lane = threadIdx.x & 63;
    int* seg = wid ? bp : bq;
    int* cur = wid ? curp : curq;
    int nseg = wid ? nbp : nbq;
    int carry = 0;
    for (int base = 0; base < nseg; base += 64) {
        int i = base + lane;
        int v = (i < nseg) ? seg[i] : 0;
        int inc = v;
        #pragma unroll
        for (int off = 1; off < 64; off <<= 1) {
            int t = __shfl_up(inc, off, 64);
            if (lane >= off) inc += t;
        }
        if (i < nseg) { int ex = carry + inc - v; seg[i] = ex; cur[i] = ex; }
        carry += __shfl(inc, 63, 64);
    }
    if (lane == 0) { if (wid == 0) rp_q[nq] = E; else rp_p[np] = E; }
}

// ---------------------------------------------------------------------------
// bscatter_conv: blocks 0..nsc-1 -> block-batched scatter of packed
//   (src<<sh | local_dst) into bucket order; blocks nsc.. -> f32->bf16
//   conversion of x_p/x_q (independent work fused to overlap).
// ---------------------------------------------------------------------------
__global__ __launch_bounds__(256) void bscatter_conv(
    const int* __restrict__ src_pv, const int* __restrict__ dst_pv,
    const int* __restrict__ src_vp, const int* __restrict__ dst_vp, int E,
    int* __restrict__ curq, int shq, int* __restrict__ curp, int shp,
    unsigned* __restrict__ pk_q, unsigned* __restrict__ pk_p, int nsc,
    const float* __restrict__ xp, unsigned short* __restrict__ xbp, int np4,
    const float* __restrict__ xq, unsigned short* __restrict__ xbq, int nq4) {
    __shared__ int cq[NBT], baq[NBT], wq[NBT];
    __shared__ int cp_[NBT], bap[NBT], wp_[NBT];
    int tid = threadIdx.x;
    int blk = blockIdx.x;
    if (blk < nsc) {
        int chunk = (E + nsc - 1) / nsc;
        int lo = blk * chunk;
        int hi = min(lo + chunk, E);
        unsigned mkq = (1u << shq) - 1, mkp = (1u << shp) - 1;
        if (tid < NBT) { cq[tid] = 0; cp_[tid] = 0; }
        __syncthreads();
        for (int e = lo + tid; e < hi; e += 256) {
            atomicAdd(&cq[dst_pv[e] >> shq], 1);
            atomicAdd(&cp_[dst_vp[e] >> shp], 1);
        }
        __syncthreads();
        if (tid < NBT) {
            baq[tid] = cq[tid]  ? atomicAdd(&curq[tid], cq[tid])  : 0; wq[tid]  = 0;
            bap[tid] = cp_[tid] ? atomicAdd(&curp[tid], cp_[tid]) : 0; wp_[tid] = 0;
        }
        __syncthreads();
        for (int e = lo + tid; e < hi; e += 256) {
            int d = dst_pv[e]; int b = d >> shq;
            int off = atomicAdd(&wq[b], 1);
            pk_q[baq[b] + off] = ((unsigned)src_pv[e] << shq) | ((unsigned)d & mkq);
            d = dst_vp[e]; b = d >> shp;
            off = atomicAdd(&wp_[b], 1);
            pk_p[bap[b] + off] = ((unsigned)src_vp[e] << shp) | ((unsigned)d & mkp);
        }
    } else {
        int tot = np4 + nq4;
        int stride = (gridDim.x - nsc) * 256;
        for (int g = (blk - nsc) * 256 + tid; g < tot; g += stride) {
            const float* src; unsigned short* dst; int i;
            if (g < np4) { src = xp; dst = xbp; i = g; }
            else         { src = xq; dst = xbq; i = g - np4; }
            float4 v = ((const float4*)src)[i];
            ushort4 o;
            o.x = f2bf(v.x); o.y = f2bf(v.y); o.z = f2bf(v.z); o.w = f2bf(v.w);
            ((ushort4*)dst)[i] = o;
        }
    }
}

// Per-bucket local CSR from packed entries.
__global__ __launch_bounds__(256) void bcsr(const unsigned* __restrict__ pk_q,
                                            const unsigned* __restrict__ pk_p,
                                            const int* __restrict__ bbq, int nbq,
                                            const int* __restrict__ bbp, int nbp,
                                            int* __restrict__ rp_q, int nq, int shq,
                                            int* __restrict__ rp_p, int np, int shp,
                                            int* __restrict__ col_q, int* __restrict__ col_p,
                                            int E) {
    int b = blockIdx.x;
    const unsigned* pk; const int* bb; int* rp; int* colg; int nb, n, sh;
    if (b < nbq) { pk = pk_q; bb = bbq; rp = rp_q; colg = col_q; nb = nbq; n = nq; sh = shq; }
    else { b -= nbq; pk = pk_p; bb = bbp; rp = rp_p; colg = col_p; nb = nbp; n = np; sh = shp; }
    int base = bb[b];
    int next = (b + 1 < nb) ? bb[b + 1] : E;
    int cnt = next - base;
    int dlo = b << sh;
    int dn  = min(1 << sh, n - dlo);
    unsigned mask = (1u << sh) - 1;

    __shared__ int deg[DNMAX];
    __shared__ int cur[DNMAX];
    __shared__ int wsum[4];
    int tid = threadIdx.x, lane = tid & 63, wid = tid >> 6;

    for (int i = tid; i < dn; i += 256) deg[i] = 0;
    __syncthreads();
    for (int i = tid; i < cnt; i += 256)
        atomicAdd(&deg[pk[base + i] & mask], 1);
    __syncthreads();

    int t2 = tid * 2;
    int d0 = (t2 < dn) ? deg[t2] : 0;
    int d1 = (t2 + 1 < dn) ? deg[t2 + 1] : 0;
    int s = d0 + d1;
    int inc = s;
    #pragma unroll
    for (int off = 1; off < 64; off <<= 1) {
        int t = __shfl_up(inc, off, 64);
        if (lane >= off) inc += t;
    }
    if (lane == 63) wsum[wid] = inc;
    __syncthreads();
    int wpre = 0;
    for (int w2 = 0; w2 < wid; ++w2) wpre += wsum[w2];
    int ex = wpre + inc - s;
    if (t2 < dn)     { cur[t2] = ex;           rp[dlo + t2] = base + ex; }
    if (t2 + 1 < dn) { cur[t2 + 1] = ex + d0;  rp[dlo + t2 + 1] = base + ex + d0; }
    __syncthreads();

    for (int i = tid; i < cnt; i += 256) {
        unsigned v = pk[base + i];
        int off = atomicAdd(&cur[v & mask], 1);
        colg[base + off] = (int)(v >> sh);
    }
}

// ---------------------------------------------------------------------------
// Tiled gather-mean, bf16 rows, 4 loads in flight (verified R10/R11)
// ---------------------------------------------------------------------------
__global__ __launch_bounds__(256) void agg_all(
    const int* __restrict__ rp_q, const int* __restrict__ col_q,
    const unsigned short* __restrict__ srcq, unsigned short* __restrict__ outq, int nq,
    const int* __restrict__ rp_p, const int* __restrict__ col_p,
    const unsigned short* __restrict__ srcp, unsigned short* __restrict__ outp, int np,
    int ntq) {
    __shared__ int rps[GT + 1];
    __shared__ int cols[GCAP];

    int blk = blockIdx.x;
    const int* rp; const int* col; const unsigned short* src; unsigned short* out; int n, d0;
    if (blk < ntq) { rp = rp_q; col = col_q; src = srcq; out = outq; n = nq; d0 = blk * GT; }
    else { rp = rp_p; col = col_p; src = srcp; out = outp; n = np; d0 = (blk - ntq) * GT; }

    int tid = threadIdx.x;
    int nrow = min(GT, n - d0);
    if (tid <= nrow) rps[tid] = rp[d0 + tid];
    __syncthreads();
    int beg0 = rps[0];
    int cnt = rps[nrow] - beg0;
    bool useLds = cnt <= GCAP;
    if (useLds)
        for (int i = tid; i < cnt; i += 256) cols[i] = col[beg0 + i];
    __syncthreads();

    int wid = tid >> 6, lane = tid & 63;
    int sub = lane >> 4;
    int ch  = lane & 15;

    for (int r = wid; r < nrow; r += 4) {
        int beg = rps[r], end = rps[r + 1];
        float a0 = 0.f, a1 = 0.f, a2 = 0.f, a3 = 0.f;
        float a4 = 0.f, a5 = 0.f, a6 = 0.f, a7 = 0.f;
        for (int i = beg; i < end; i += 16) {
            uint4 v[4]; bool act[4];
            #pragma unroll
            for (int h2 = 0; h2 < 4; ++h2) {
                int j = i + h2 * 4 + sub;
                act[h2] = j < end;
                if (act[h2]) {
                    int s = useLds ? cols[j - beg0] : col[j];
                    v[h2] = *(const uint4*)(src + (size_t)s * D + ch * 8);
                }
            }
            #pragma unroll
            for (int h2 = 0; h2 < 4; ++h2) {
                if (act[h2]) {
                    union { unsigned u; float f; } t;
                    t.u = v[h2].x << 16;         a0 += t.f;
                    t.u = v[h2].x & 0xffff0000u; a1 += t.f;
                    t.u = v[h2].y << 16;         a2 += t.f;
                    t.u = v[h2].y & 0xffff0000u; a3 += t.f;
                    t.u = v[h2].z << 16;         a4 += t.f;
                    t.u = v[h2].z & 0xffff0000u; a5 += t.f;
                    t.u = v[h2].w << 16;         a6 += t.f;
                    t.u = v[h2].w & 0xffff0000u; a7 += t.f;
                }
            }
        }
        #pragma unroll
        for (int off = 16; off <= 32; off <<= 1) {
            a0 += __shfl_xor(a0, off); a1 += __shfl_xor(a1, off);
            a2 += __shfl_xor(a2, off); a3 += __shfl_xor(a3, off);
            a4 += __shfl_xor(a4, off); a5 += __shfl_xor(a5, off);
            a6 += __shfl_xor(a6, off); a7 += __shfl_xor(a7, off);
        }
        int deg = end - beg;
        float inv = (deg > 0) ? 1.0f / (float)deg : 0.f;
        if (sub == 0) {
            uint4 o;
            o.x = (unsigned)f2bf(a0 * inv) | ((unsigned)f2bf(a1 * inv) << 16);
            o.y = (unsigned)f2bf(a2 * inv) | ((unsigned)f2bf(a3 * inv) << 16);
            o.z = (unsigned)f2bf(a4 * inv) | ((unsigned)f2bf(a5 * inv) << 16);
            o.w = (unsigned)f2bf(a6 * inv) | ((unsigned)f2bf(a7 * inv) << 16);
            *(uint4*)(out + (size_t)(d0 + r) * D + ch * 8) = o;
        }
    }
}

// ---------------------------------------------------------------------------
// MFMA dual GEMM body (all-bf16 A, hi/lo split W, 2 MFMAs/k-step)
// WF32: write f32 out. WHB: write bf16 hb.
// ---------------------------------------------------------------------------
struct GemmSide {
    const unsigned short* A1;
    const unsigned short* A2;
    const unsigned short* Wt1;
    const unsigned short* Wt2;
    const float* bias;
    float* out;
    unsigned short* hb;
    int n;
};

template <bool RELU, bool WF32, bool WHB>
__device__ __forceinline__ void gemm_body(const GemmSide& S, int bidx) {
    __shared__ unsigned short As[128][PAD];
    __shared__ unsigned short Ws_hi[128][PAD];
    __shared__ unsigned short Ws_lo[128][PAD];

    const int tid  = threadIdx.x;
    const int lane = tid & 63;
    const int w    = tid >> 6;
    const int m0   = bidx * 128;
    const int n    = S.n;

    f32x4 acc[2][8];
    #pragma unroll
    for (int i = 0; i < 2; ++i)
        #pragma unroll
        for (int j = 0; j < 8; ++j) acc[i][j] = (f32x4)0.f;

    const int srow  = tid >> 1;
    const int skoff = (tid & 1) * 16;

    for (int ks = 0; ks < 8; ++ks) {
        const int half = ks >> 2;
        const int kb   = (ks & 3) * 32;
        const unsigned short* A  = half ? S.A2 : S.A1;
        const unsigned short* Wt = half ? S.Wt2 : S.Wt1;

        {
            int grow = m0 + srow;
            if (grow >= n) grow = n - 1;
            const uint4* pa = (const uint4*)(A + (size_t)grow * D + kb + skoff);
            ((uint4*)&As[srow][skoff])[0] = pa[0];
            ((uint4*)&As[srow][skoff])[1] = pa[1];
        }
        {
            const uint4* ph = (const uint4*)(Wt + (size_t)srow * D + kb + skoff);
            ((uint4*)&Ws_hi[srow][skoff])[0] = ph[0];
            ((uint4*)&Ws_hi[srow][skoff])[1] = ph[1];
            const uint4* pl = (const uint4*)(Wt + 16384 + (size_t)srow * D + kb + skoff);
            ((uint4*)&Ws_lo[srow][skoff])[0] = pl[0];
            ((uint4*)&Ws_lo[srow][skoff])[1] = pl[1];
        }
        __syncthreads();

        const int r0 = w * 32;
        const int k8 = (lane >> 4) * 8;
        const int li = lane & 15;

        short8 ah[2];
        #pragma unroll
        for (int m = 0; m < 2; ++m)
            ah[m] = *(const short8*)&As[r0 + m * 16 + li][k8];
        #pragma unroll
        for (int nb = 0; nb < 8; ++nb) {
            int cc = nb * 16 + li;
            short8 bh = *(const short8*)&Ws_hi[cc][k8];
            short8 bl = *(const short8*)&Ws_lo[cc][k8];
            #pragma unroll
            for (int m = 0; m < 2; ++m) {
                acc[m][nb] = __builtin_amdgcn_mfma_f32_16x16x32_bf16(ah[m], bh, acc[m][nb], 0, 0, 0);
                acc[m][nb] = __builtin_amdgcn_mfma_f32_16x16x32_bf16(ah[m], bl, acc[m][nb], 0, 0, 0);
            }
        }
        __syncthreads();
    }

    const int li = lane & 15;
    const int rq = (lane >> 4) * 4;
    float bv[8];
    #pragma unroll
    for (int nb = 0; nb < 8; ++nb) bv[nb] = S.bias[nb * 16 + li];

    #pragma unroll
    for (int m = 0; m < 2; ++m) {
        #pragma unroll
        for (int nb = 0; nb < 8; ++nb) {
            #pragma unroll
            for (int r = 0; r < 4; ++r) {
                int R = m0 + w * 32 + m * 16 + rq + r;
                if (R < n) {
                    int C = nb * 16 + li;
                    float v = acc[m][nb][r] + bv[nb];
                    if (RELU) v = fmaxf(v, 0.f);
                    if (WF32) S.out[(size_t)R * D + C] = v;
                    if (WHB)  S.hb[(size_t)R * D + C] = f2bf(v);
                }
            }
        }
    }
}

template <bool RELU, bool WF32, bool WHB>
__global__ __launch_bounds__(256) void gemm_both(GemmSide Sq, GemmSide Sp, int mq) {
    if ((int)blockIdx.x < mq) gemm_body<RELU, WF32, WHB>(Sq, blockIdx.x);
    else                      gemm_body<RELU, WF32, WHB>(Sp, blockIdx.x - mq);
}

// ---------------------------------------------------------------------------
extern "C" void kernel_launch(void* const* d_in, const int* in_sizes, int n_in,
                              void* d_out, int out_size, void* d_ws, size_t ws_size,
                              hipStream_t stream) {
    const float* x_p = (const float*)d_in[0];
    const float* x_q = (const float*)d_in[1];
    const int* src_pv = (const int*)d_in[2];
    const int* dst_pv = (const int*)d_in[3];
    const int* src_vp = (const int*)d_in[4];
    const int* dst_vp = (const int*)d_in[5];
    const float* Wl_pv0 = (const float*)d_in[6];
    const float* Wr_pv0 = (const float*)d_in[7];
    const float* b_pv0  = (const float*)d_in[8];
    const float* Wl_vp0 = (const float*)d_in[9];
    const float* Wr_vp0 = (const float*)d_in[10];
    const float* b_vp0  = (const float*)d_in[11];
    const float* Wl_pv1 = (const float*)d_in[12];
    const float* Wr_pv1 = (const float*)d_in[13];
    const float* b_pv1  = (const float*)d_in[14];
    const float* Wl_vp1 = (const float*)d_in[15];
    const float* Wr_vp1 = (const float*)d_in[16];
    const float* b_vp1  = (const float*)d_in[17];

    const int NP = in_sizes[0] / D;
    const int NQ = in_sizes[1] / D;
    const int E  = in_sizes[2];

    float* out_p = (float*)d_out;
    float* out_q = out_p + (size_t)NP * D;

    int shq = 6; while ((((NQ - 1) >> shq) + 1) > NBT) ++shq;
    int shp = 6; while ((((NP - 1) >> shp) + 1) > NBT) ++shp;
    int nbq = ((NQ - 1) >> shq) + 1;
    int nbp = ((NP - 1) >> shp) + 1;

    // workspace layout
    char* ws = (char*)d_ws;
    int* rp_q  = (int*)ws;
    int* rp_p  = rp_q + (NQ + 1);
    int* col_q = rp_p + (NP + 1);
    int* col_p = col_q + E;
    int* bq    = col_p + E;
    int* bp    = bq + NBT;
    int* curq  = bp + NBT;
    int* curp  = curq + NBT;
    size_t int_bytes = ((size_t)(NQ + 1) + (NP + 1) + 2 * (size_t)E + 4 * NBT) * sizeof(int);
    int_bytes = (int_bytes + 511) & ~(size_t)511;
    unsigned short* wt = (unsigned short*)(ws + int_bytes);
    size_t wt_bytes = ((size_t)8 * 32768 * sizeof(unsigned short) + 511) & ~(size_t)511;
    unsigned short* xb_p = (unsigned short*)(ws + int_bytes + wt_bytes);  // NP*128
    unsigned short* xb_q = xb_p + (size_t)NP * D;                          // NQ*128
    unsigned short* hb_p = xb_p;   // alias (block-local in-place, see gemm)
    unsigned short* hb_q = xb_q;
    unsigned short* aggb_q = xb_q + (size_t)NQ * D;                        // NQ*128
    unsigned short* aggb_p = aggb_q + (size_t)NQ * D;                      // NP*128
    unsigned* pk_q = (unsigned*)aggb_q;   // alias (dead before first agg write)
    unsigned* pk_p = pk_q + E;

    // --- prep (W split + hist; bq/bp zeroed first) ---
    hipMemsetAsync(bq, 0, 2 * NBT * sizeof(int), stream);
    prep_hist<<<320, 256, 0, stream>>>(Wl_pv0, Wr_pv0, Wl_vp0, Wr_vp0,
                                       Wl_pv1, Wr_pv1, Wl_vp1, Wr_vp1, wt,
                                       dst_pv, dst_vp, E, shq, shp, bq, bp);

    // --- CSR build (x->bf16 conversion fused into bscatter to overlap) ---
    bscan<<<1, 128, 0, stream>>>(bq, nbq, bp, nbp, curq, curp, rp_q, NQ, rp_p, NP, E);
    bscatter_conv<<<512 + 2048, 256, 0, stream>>>(src_pv, dst_pv, src_vp, dst_vp, E,
                                                  curq, shq, curp, shp, pk_q, pk_p, 512,
                                                  x_p, xb_p, NP * D / 4, x_q, xb_q, NQ * D / 4);
    bcsr<<<nbq + nbp, 256, 0, stream>>>(pk_q, pk_p, bq, nbq, bp, nbp,
                                        rp_q, NQ, shq, rp_p, NP, shp, col_q, col_p, E);

    int ntq = (NQ + GT - 1) / GT, ntp = (NP + GT - 1) / GT;
    int mq = (NQ + 127) / 128, mp = (NP + 127) / 128;

    GemmSide Sq0 = { aggb_q, xb_q, wt + 0 * 32768, wt + 1 * 32768, b_pv0, out_q, hb_q, NQ };
    GemmSide Sp0 = { aggb_p, xb_p, wt + 2 * 32768, wt + 3 * 32768, b_vp0, out_p, hb_p, NP };
    GemmSide Sq1 = { aggb_q, hb_q, wt + 4 * 32768, wt + 5 * 32768, b_pv1, out_q, nullptr, NQ };
    GemmSide Sp1 = { aggb_p, hb_p, wt + 6 * 32768, wt + 7 * 32768, b_vp1, out_p, nullptr, NP };

    // --- layer 0 (f32 out stores dead; write bf16 h1 only) ---
    agg_all<<<ntq + ntp, 256, 0, stream>>>(rp_q, col_q, xb_p, aggb_q, NQ,
                                           rp_p, col_p, xb_q, aggb_p, NP, ntq);
    gemm_both<true, false, true><<<mq + mp, 256, 0, stream>>>(Sq0, Sp0, mq);

    // --- layer 1 ---
    agg_all<<<ntq + ntp, 256, 0, stream>>>(rp_q, col_q, hb_p, aggb_q, NQ,
                                           rp_p, col_p, hb_q, aggb_p, NP, ntq);
    gemm_both<false, true, false><<<mq + mp, 256, 0, stream>>>(Sq1, Sp1, mq);
}